// Round 3
// baseline (272.707 us; speedup 1.0000x reference)
//
#include <hip/hip_runtime.h>
#include <stdint.h>
#include <stddef.h>

#define B_ 4
#define T_ 8192
#define D_ 1024
#define NBLK 64
#define SEGL 128
#define TOPK_ 16
#define NS 21          // 16 micro + 4 macro + 1 glob
#define MPAD 96
#define RMS_EPS_ 1.1920929e-07f

typedef float f32x4 __attribute__((ext_vector_type(4)));
typedef __bf16 bf16x8 __attribute__((ext_vector_type(8)));
typedef unsigned short us8 __attribute__((ext_vector_type(8)));

__device__ __forceinline__ unsigned short f2bf(float f) {
    union { float f; unsigned int u; } v; v.f = f;
    unsigned int r = v.u + 0x7FFFu + ((v.u >> 16) & 1u);
    return (unsigned short)(r >> 16);
}
__device__ __forceinline__ float4 ld4(const float* p) { return *(const float4*)p; }

// ---------------------------------------------------------------------------
// K1: per-(b,blk) segment mean (fp32), hid_score = ||mean||, sur_score = mean(nll)
// grid 256 (b*64+blk), block 512. Streams all 128 MB of prev_hidden, coalesced float4.
// ---------------------------------------------------------------------------
__global__ __launch_bounds__(512) void seg_stats(
        const float* __restrict__ ph, const float* __restrict__ nll,
        float* __restrict__ seg_mean, float* __restrict__ hid, float* __restrict__ sur) {
    int g = blockIdx.x; int b = g >> 6; int blk = g & 63;
    int tid = threadIdx.x; int half = tid >> 8; int c = tid & 255;
    const float* base = ph + ((size_t)b * T_ + blk * SEGL + half * 64) * D_ + 4 * c;
    float ax = 0.f, ay = 0.f, az = 0.f, aw = 0.f;
    #pragma unroll 8
    for (int r = 0; r < 64; r++) {
        float4 v = ld4(base + (size_t)r * D_);
        ax += v.x; ay += v.y; az += v.z; aw += v.w;
    }
    __shared__ float4 tmp[256];
    __shared__ float red[256];
    __shared__ float nl[128];
    if (tid < 128) nl[tid] = nll[b * T_ + blk * SEGL + tid];
    if (half) { float4 t; t.x = ax; t.y = ay; t.z = az; t.w = aw; tmp[c] = t; }
    __syncthreads();
    if (!half) {
        float4 t2 = tmp[c];
        float mx = (ax + t2.x) * (1.f/128.f), my = (ay + t2.y) * (1.f/128.f);
        float mz = (az + t2.z) * (1.f/128.f), mw = (aw + t2.w) * (1.f/128.f);
        float4 m; m.x = mx; m.y = my; m.z = mz; m.w = mw;
        *(float4*)(seg_mean + (size_t)g * D_ + 4 * c) = m;
        red[c] = mx*mx + my*my + mz*mz + mw*mw;
    }
    __syncthreads();
    for (int s2 = 128; s2 > 0; s2 >>= 1) { if (tid < s2) red[tid] += red[tid + s2]; __syncthreads(); }
    for (int s2 = 64;  s2 > 0; s2 >>= 1) { if (tid < s2) nl[tid]  += nl[tid + s2];  __syncthreads(); }
    if (tid == 0) { hid[g] = sqrtf(red[0]); sur[g] = nl[0] * (1.f/128.f); }
}

// ---------------------------------------------------------------------------
// K3: fused top-k + feats assembly (MPAD x 2048) bf16. Each block redundantly
// recomputes its batch's zscore+rank top-16 (64 values, L2-hot) -> no separate
// topk launch. Rows >=84 zero-padded.
// ---------------------------------------------------------------------------
__global__ __launch_bounds__(256) void feats_build(
        const float* __restrict__ ph, const float* __restrict__ seg_mean,
        const float* __restrict__ hid, const float* __restrict__ sur,
        unsigned short* __restrict__ feats) {
    int r = blockIdx.x; int t = threadIdx.x;
    unsigned short* row0 = feats + (size_t)r * 2048 + 4 * t;          // mean half
    unsigned short* row1 = row0 + 1024;                                // last half
    if (r >= B_ * NS) {
        ushort4 z4; z4.x = z4.y = z4.z = z4.w = 0;
        *(ushort4*)row0 = z4; *(ushort4*)row1 = z4;
        return;
    }
    int b = r / NS, s = r % NS;
    __shared__ float sc[64];
    __shared__ int sidx[16];
    if (t < 64) {
        float h = hid[b * NBLK + t];
        float ss0 = sur[b * NBLK + t];
        float mh = h; for (int o = 32; o; o >>= 1) mh += __shfl_xor(mh, o); mh *= (1.f/64.f);
        float dh = h - mh; float vh = dh * dh;
        for (int o = 32; o; o >>= 1) vh += __shfl_xor(vh, o); vh *= (1.f/64.f);
        float sh = fmaxf(sqrtf(vh), 1e-6f);
        float ms = ss0; for (int o = 32; o; o >>= 1) ms += __shfl_xor(ms, o); ms *= (1.f/64.f);
        float ds = ss0 - ms; float vs = ds * ds;
        for (int o = 32; o; o >>= 1) vs += __shfl_xor(vs, o); vs *= (1.f/64.f);
        float ssd = fmaxf(sqrtf(vs), 1e-6f);
        sc[t] = dh / sh + ds / ssd;
    }
    __syncthreads();
    if (t < 64) {
        float z = sc[t];
        int rank = 0;
        for (int j = 0; j < 64; j++) {
            float oj = sc[j];
            rank += (oj > z) || (oj == z && j < t);
        }
        bool sel = rank < TOPK_;
        unsigned long long mask = __ballot(sel);
        int pos = __popcll(mask & ((1ull << t) - 1ull));
        if (sel) sidx[pos] = t;
    }
    __syncthreads();

    float mx = 0, my = 0, mz = 0, mw = 0;
    int lastrow;
    if (s < 16) {
        int blk = sidx[s];
        float4 v = ld4(seg_mean + (size_t)(b * NBLK + blk) * D_ + 4 * t);
        mx = v.x; my = v.y; mz = v.z; mw = v.w;
        lastrow = blk * SEGL + SEGL - 1;
    } else if (s < 20) {
        int m = s - 16;
        for (int j = 0; j < 16; j++) {
            float4 v = ld4(seg_mean + (size_t)(b * NBLK + m * 16 + j) * D_ + 4 * t);
            mx += v.x; my += v.y; mz += v.z; mw += v.w;
        }
        mx *= (1.f/16.f); my *= (1.f/16.f); mz *= (1.f/16.f); mw *= (1.f/16.f);
        lastrow = m * 2048 + 2047;
    } else {
        for (int j = 0; j < 64; j++) {
            float4 v = ld4(seg_mean + (size_t)(b * NBLK + j) * D_ + 4 * t);
            mx += v.x; my += v.y; mz += v.z; mw += v.w;
        }
        mx *= (1.f/64.f); my *= (1.f/64.f); mz *= (1.f/64.f); mw *= (1.f/64.f);
        lastrow = T_ - 1;
    }
    float4 lv = ld4(ph + ((size_t)b * T_ + lastrow) * D_ + 4 * t);
    ushort4 hm; hm.x = f2bf(mx); hm.y = f2bf(my); hm.z = f2bf(mz); hm.w = f2bf(mw);
    ushort4 hl; hl.x = f2bf(lv.x); hl.y = f2bf(lv.y); hl.z = f2bf(lv.z); hl.w = f2bf(lv.w);
    *(ushort4*)row0 = hm;
    *(ushort4*)row1 = hl;
}

// ---------------------------------------------------------------------------
// K4 (v3): bf16 MFMA GEMM  C[96x1024] = A[96xK] @ Bw[1024xK]^T
// One block per 16-col n-strip (weight rows read exactly once). 512 threads =
// 8 waves split-K 8-way, all six 16-row M-tiles per block, no K-loop barriers.
// MODE 0: A bf16, write Cf/Cb.
// MODE 1: A bf16, write Cf + per-row sum-of-squares atomicAdd into sumsq[96]
//         (feeds the fused RMSNorm downstream).
// MODE 2: A fp32 scaled by rsqrt(sumsq/1024+eps) per row (fused RMSNorm),
//         blockIdx.y picks weight set {B0->C0} / {B1->C1} (fused K+V).
// Split-K reduced through 48 KB LDS.
// ---------------------------------------------------------------------------
template<int K, int MODE>
__global__ __launch_bounds__(512) void gemm_v3(
        const void* __restrict__ Av,
        const float* __restrict__ B0, const float* __restrict__ B1,
        float* __restrict__ C0f, unsigned short* __restrict__ C0b,
        float* __restrict__ C1f, unsigned short* __restrict__ C1b,
        float* __restrict__ sumsq) {
    constexpr int KW = K / 8;
    constexpr int NSTEP = KW / 32;
    const float* Bw = (MODE == 2 && blockIdx.y) ? B1 : B0;
    float* Cf          = (MODE == 2 && blockIdx.y) ? C1f : C0f;
    unsigned short* Cb = (MODE == 2 && blockIdx.y) ? C1b : C0b;

    int n0 = blockIdx.x * 16;
    int tid = threadIdx.x, wave = tid >> 6, lane = tid & 63;
    int quad = lane >> 4, l16 = lane & 15;
    int kbase = wave * KW;

    f32x4 acc[6];
    #pragma unroll
    for (int i = 0; i < 6; i++) acc[i] = (f32x4){0.f, 0.f, 0.f, 0.f};

    float scl[6];
    if (MODE == 2) {
        #pragma unroll
        for (int mi = 0; mi < 6; mi++)
            scl[mi] = rsqrtf(sumsq[mi * 16 + l16] * (1.f/1024.f) + RMS_EPS_);
    }

    const float* bp = Bw + (size_t)(n0 + l16) * K + kbase + quad * 8;

    #pragma unroll 4
    for (int s = 0; s < NSTEP; s++) {
        float4 b0 = ld4(bp + s * 32);
        float4 b1 = ld4(bp + s * 32 + 4);
        us8 braw;
        braw[0] = f2bf(b0.x); braw[1] = f2bf(b0.y); braw[2] = f2bf(b0.z); braw[3] = f2bf(b0.w);
        braw[4] = f2bf(b1.x); braw[5] = f2bf(b1.y); braw[6] = f2bf(b1.z); braw[7] = f2bf(b1.w);
        bf16x8 bfr = __builtin_bit_cast(bf16x8, braw);
        #pragma unroll
        for (int mi = 0; mi < 6; mi++) {
            bf16x8 af;
            if (MODE == 2) {
                const float* apf = (const float*)Av + (size_t)(mi * 16 + l16) * K + kbase + quad * 8 + s * 32;
                float4 a0 = ld4(apf), a1 = ld4(apf + 4);
                us8 ar;
                ar[0] = f2bf(a0.x * scl[mi]); ar[1] = f2bf(a0.y * scl[mi]);
                ar[2] = f2bf(a0.z * scl[mi]); ar[3] = f2bf(a0.w * scl[mi]);
                ar[4] = f2bf(a1.x * scl[mi]); ar[5] = f2bf(a1.y * scl[mi]);
                ar[6] = f2bf(a1.z * scl[mi]); ar[7] = f2bf(a1.w * scl[mi]);
                af = __builtin_bit_cast(bf16x8, ar);
            } else {
                af = __builtin_bit_cast(bf16x8,
                    *(const us8*)((const unsigned short*)Av + (size_t)(mi * 16 + l16) * K + kbase + quad * 8 + s * 32));
            }
            acc[mi] = __builtin_amdgcn_mfma_f32_16x16x32_bf16(af, bfr, acc[mi], 0, 0, 0);
        }
    }

    __shared__ float part[8][6][16][16];   // 48 KB
    #pragma unroll
    for (int mi = 0; mi < 6; mi++)
        #pragma unroll
        for (int r = 0; r < 4; r++)
            part[wave][mi][quad * 4 + r][l16] = acc[mi][r];
    __syncthreads();

    #pragma unroll
    for (int j = 0; j < 3; j++) {
        int o = tid + j * 512;
        int mi = o >> 8, rr = (o >> 4) & 15, cc = o & 15;
        float v = 0.f;
        #pragma unroll
        for (int w = 0; w < 8; w++) v += part[w][mi][rr][cc];
        int row = mi * 16 + rr, col = n0 + cc;
        if (MODE == 1) {
            float v2 = v * v;
            #pragma unroll
            for (int off = 1; off < 16; off <<= 1) v2 += __shfl_xor(v2, off);
            if ((tid & 15) == 0) atomicAdd(&sumsq[row], v2);
        }
        if (Cf) Cf[(size_t)row * 1024 + col] = v;
        if (Cb) Cb[(size_t)row * 1024 + col] = f2bf(v);
    }
}

// ---------------------------------------------------------------------------
// K6: per-(b,q) logits (query . keys)/32, softmax over 21, out = attn @ valsO.
// grid 256 (b*64+q), block 256 (4 waves).
// ---------------------------------------------------------------------------
__global__ __launch_bounds__(256) void attn_out(
        const float* __restrict__ query, const float* __restrict__ keys,
        const float* __restrict__ valsO, float* __restrict__ out) {
    int g = blockIdx.x; int b = g >> 6; int q = g & 63;
    int tid = threadIdx.x, wave = tid >> 6, lane = tid & 63;
    __shared__ float attnw[24];
    const float* qrow = query + (size_t)q * D_ + lane * 16;
    float4 qv0 = ld4(qrow), qv1 = ld4(qrow + 4), qv2 = ld4(qrow + 8), qv3 = ld4(qrow + 12);
    for (int s = wave; s < NS; s += 4) {
        const float* krow = keys + (size_t)(b * NS + s) * D_ + lane * 16;
        float4 k0 = ld4(krow), k1 = ld4(krow + 4), k2 = ld4(krow + 8), k3 = ld4(krow + 12);
        float a = qv0.x*k0.x + qv0.y*k0.y + qv0.z*k0.z + qv0.w*k0.w
                + qv1.x*k1.x + qv1.y*k1.y + qv1.z*k1.z + qv1.w*k1.w
                + qv2.x*k2.x + qv2.y*k2.y + qv2.z*k2.z + qv2.w*k2.w
                + qv3.x*k3.x + qv3.y*k3.y + qv3.z*k3.z + qv3.w*k3.w;
        for (int o = 32; o; o >>= 1) a += __shfl_xor(a, o);
        if (lane == 0) attnw[s] = a * 0.03125f;   // /sqrt(1024)
    }
    __syncthreads();
    if (tid == 0) {
        float mx = -1e30f;
        for (int s = 0; s < NS; s++) mx = fmaxf(mx, attnw[s]);
        float sum = 0.f;
        for (int s = 0; s < NS; s++) { float e = expf(attnw[s] - mx); attnw[s] = e; sum += e; }
        float inv = 1.f / sum;
        for (int s = 0; s < NS; s++) attnw[s] *= inv;
    }
    __syncthreads();
    float ax = 0, ay = 0, az = 0, aw = 0;
    #pragma unroll
    for (int s = 0; s < NS; s++) {
        float w = attnw[s];
        float4 v = ld4(valsO + (size_t)(b * NS + s) * D_ + 4 * tid);
        ax += w * v.x; ay += w * v.y; az += w * v.z; aw += w * v.w;
    }
    float4 o4; o4.x = ax; o4.y = ay; o4.z = az; o4.w = aw;
    *(float4*)(out + (size_t)g * D_ + 4 * tid) = o4;
}

// ---------------------------------------------------------------------------
extern "C" void kernel_launch(void* const* d_in, const int* in_sizes, int n_in,
                              void* d_out, int out_size, void* d_ws, size_t ws_size,
                              hipStream_t stream) {
    (void)in_sizes; (void)n_in; (void)out_size; (void)ws_size;
    const float* ph    = (const float*)d_in[0];
    const float* nll   = (const float*)d_in[1];
    const float* query = (const float*)d_in[2];
    const float* W_sum = (const float*)d_in[3];
    const float* W_k   = (const float*)d_in[4];
    const float* W_v   = (const float*)d_in[5];
    const float* W_o   = (const float*)d_in[6];
    float* out = (float*)d_out;

    char* ws = (char*)d_ws;
    float*          seg_mean = (float*)(ws + 0);                 // 1048576 B
    float*          hid      = (float*)(ws + 1048576);           // 1024 B
    float*          sur      = (float*)(ws + 1049600);           // 1024 B
    float*          sumsq    = (float*)(ws + 1050624);           // 384 B (96 f32)
    unsigned short* feats    = (unsigned short*)(ws + 1051136);  // 393216 B
    float*          presum_f = (float*)(ws + 1444352);           // 393216 B
    float*          keys_f   = (float*)(ws + 1837568);           // 393216 B
    unsigned short* vals_b   = (unsigned short*)(ws + 2230784);  // 196608 B
    float*          valsO_f  = (float*)(ws + 2427392);           // 393216 B

    hipMemsetAsync(sumsq, 0, MPAD * sizeof(float), stream);
    seg_stats<<<B_ * NBLK, 512, 0, stream>>>(ph, nll, seg_mean, hid, sur);
    feats_build<<<MPAD, 256, 0, stream>>>(ph, seg_mean, hid, sur, feats);
    gemm_v3<2048, 1><<<dim3(64, 1), 512, 0, stream>>>(
        feats, W_sum, nullptr, presum_f, nullptr, nullptr, nullptr, sumsq);
    gemm_v3<1024, 2><<<dim3(64, 2), 512, 0, stream>>>(
        presum_f, W_k, W_v, keys_f, nullptr, nullptr, vals_b, sumsq);
    gemm_v3<1024, 0><<<dim3(64, 1), 512, 0, stream>>>(
        vals_b, W_o, nullptr, valsO_f, nullptr, nullptr, nullptr, nullptr);
    attn_out<<<B_ * NBLK, 256, 0, stream>>>(query, keys_f, valsO_f, out);
}

// Round 5
// 256.378 us; speedup vs baseline: 1.0637x; 1.0637x over previous
//
#include <hip/hip_runtime.h>
#include <stdint.h>
#include <stddef.h>

#define B_ 4
#define T_ 8192
#define D_ 1024
#define NBLK 64
#define SEGL 128
#define TOPK_ 16
#define NS 21          // 16 micro + 4 macro + 1 glob
#define MPAD 96
#define RMS_EPS_ 1.1920929e-07f
#define PART 98304     // 96*1024, one partial-C slice

typedef float f32x4 __attribute__((ext_vector_type(4)));
typedef __bf16 bf16x8 __attribute__((ext_vector_type(8)));
typedef unsigned short us8 __attribute__((ext_vector_type(8)));

__device__ __forceinline__ unsigned short f2bf(float f) {
    union { float f; unsigned int u; } v; v.f = f;
    unsigned int r = v.u + 0x7FFFu + ((v.u >> 16) & 1u);
    return (unsigned short)(r >> 16);
}
__device__ __forceinline__ float4 ld4(const float* p) { return *(const float4*)p; }

// ---------------------------------------------------------------------------
// K1: per-(b,blk) segment mean (fp32), hid_score = ||mean||, sur_score = mean(nll)
// ---------------------------------------------------------------------------
__global__ __launch_bounds__(512) void seg_stats(
        const float* __restrict__ ph, const float* __restrict__ nll,
        float* __restrict__ seg_mean, float* __restrict__ hid, float* __restrict__ sur) {
    int g = blockIdx.x; int b = g >> 6; int blk = g & 63;
    int tid = threadIdx.x; int half = tid >> 8; int c = tid & 255;
    const float* base = ph + ((size_t)b * T_ + blk * SEGL + half * 64) * D_ + 4 * c;
    float ax = 0.f, ay = 0.f, az = 0.f, aw = 0.f;
    #pragma unroll 8
    for (int r = 0; r < 64; r++) {
        float4 v = ld4(base + (size_t)r * D_);
        ax += v.x; ay += v.y; az += v.z; aw += v.w;
    }
    __shared__ float4 tmp[256];
    __shared__ float red[256];
    __shared__ float nl[128];
    if (tid < 128) nl[tid] = nll[b * T_ + blk * SEGL + tid];
    if (half) { float4 t; t.x = ax; t.y = ay; t.z = az; t.w = aw; tmp[c] = t; }
    __syncthreads();
    if (!half) {
        float4 t2 = tmp[c];
        float mx = (ax + t2.x) * (1.f/128.f), my = (ay + t2.y) * (1.f/128.f);
        float mz = (az + t2.z) * (1.f/128.f), mw = (aw + t2.w) * (1.f/128.f);
        float4 m; m.x = mx; m.y = my; m.z = mz; m.w = mw;
        *(float4*)(seg_mean + (size_t)g * D_ + 4 * c) = m;
        red[c] = mx*mx + my*my + mz*mz + mw*mw;
    }
    __syncthreads();
    for (int s2 = 128; s2 > 0; s2 >>= 1) { if (tid < s2) red[tid] += red[tid + s2]; __syncthreads(); }
    for (int s2 = 64;  s2 > 0; s2 >>= 1) { if (tid < s2) nl[tid]  += nl[tid + s2];  __syncthreads(); }
    if (tid == 0) { hid[g] = sqrtf(red[0]); sur[g] = nl[0] * (1.f/128.f); }
}

// ---------------------------------------------------------------------------
// K2: fused top-k + feats assembly (MPAD x 2048) bf16.
// ---------------------------------------------------------------------------
__global__ __launch_bounds__(256) void feats_build(
        const float* __restrict__ ph, const float* __restrict__ seg_mean,
        const float* __restrict__ hid, const float* __restrict__ sur,
        unsigned short* __restrict__ feats) {
    int r = blockIdx.x; int t = threadIdx.x;
    unsigned short* row0 = feats + (size_t)r * 2048 + 4 * t;
    unsigned short* row1 = row0 + 1024;
    if (r >= B_ * NS) {
        ushort4 z4; z4.x = z4.y = z4.z = z4.w = 0;
        *(ushort4*)row0 = z4; *(ushort4*)row1 = z4;
        return;
    }
    int b = r / NS, s = r % NS;
    __shared__ float sc[64];
    __shared__ int sidx[16];
    if (t < 64) {
        float h = hid[b * NBLK + t];
        float ss0 = sur[b * NBLK + t];
        float mh = h; for (int o = 32; o; o >>= 1) mh += __shfl_xor(mh, o); mh *= (1.f/64.f);
        float dh = h - mh; float vh = dh * dh;
        for (int o = 32; o; o >>= 1) vh += __shfl_xor(vh, o); vh *= (1.f/64.f);
        float sh = fmaxf(sqrtf(vh), 1e-6f);
        float ms = ss0; for (int o = 32; o; o >>= 1) ms += __shfl_xor(ms, o); ms *= (1.f/64.f);
        float ds = ss0 - ms; float vs = ds * ds;
        for (int o = 32; o; o >>= 1) vs += __shfl_xor(vs, o); vs *= (1.f/64.f);
        float ssd = fmaxf(sqrtf(vs), 1e-6f);
        sc[t] = dh / sh + ds / ssd;
    }
    __syncthreads();
    if (t < 64) {
        float z = sc[t];
        int rank = 0;
        for (int j = 0; j < 64; j++) {
            float oj = sc[j];
            rank += (oj > z) || (oj == z && j < t);
        }
        bool sel = rank < TOPK_;
        unsigned long long mask = __ballot(sel);
        int pos = __popcll(mask & ((1ull << t) - 1ull));
        if (sel) sidx[pos] = t;
    }
    __syncthreads();

    float mx = 0, my = 0, mz = 0, mw = 0;
    int lastrow;
    if (s < 16) {
        int blk = sidx[s];
        float4 v = ld4(seg_mean + (size_t)(b * NBLK + blk) * D_ + 4 * t);
        mx = v.x; my = v.y; mz = v.z; mw = v.w;
        lastrow = blk * SEGL + SEGL - 1;
    } else if (s < 20) {
        int m = s - 16;
        for (int j = 0; j < 16; j++) {
            float4 v = ld4(seg_mean + (size_t)(b * NBLK + m * 16 + j) * D_ + 4 * t);
            mx += v.x; my += v.y; mz += v.z; mw += v.w;
        }
        mx *= (1.f/16.f); my *= (1.f/16.f); mz *= (1.f/16.f); mw *= (1.f/16.f);
        lastrow = m * 2048 + 2047;
    } else {
        for (int j = 0; j < 64; j++) {
            float4 v = ld4(seg_mean + (size_t)(b * NBLK + j) * D_ + 4 * t);
            mx += v.x; my += v.y; mz += v.z; mw += v.w;
        }
        mx *= (1.f/64.f); my *= (1.f/64.f); mz *= (1.f/64.f); mw *= (1.f/64.f);
        lastrow = T_ - 1;
    }
    float4 lv = ld4(ph + ((size_t)b * T_ + lastrow) * D_ + 4 * t);
    ushort4 hm; hm.x = f2bf(mx); hm.y = f2bf(my); hm.z = f2bf(mz); hm.w = f2bf(mw);
    ushort4 hl; hl.x = f2bf(lv.x); hl.y = f2bf(lv.y); hl.z = f2bf(lv.z); hl.w = f2bf(lv.w);
    *(ushort4*)row0 = hm;
    *(ushort4*)row1 = hl;
}

// ---------------------------------------------------------------------------
// K4 (v4b): LDS-staged coalesced MFMA GEMM with block-level split-K.
// C[96x1024] = A[96xK] @ Bw[1024xK]^T, written as per-k-chunk partial slices
// at Cp + kc*PART (bug fix vs v4: v4 dropped the kc offset -> all chunks raced
// on slice 0). Block = 64-col n-strip x 256-wide k-chunk, 512 threads.
// Stage B 64x256 fp32->bf16 + A 96x256 bf16 (wave-contiguous 16 B/lane reads),
// one barrier, 24 MFMAs/wave from LDS (row stride 264). Waves = 4 n-substrips
// x 2 k-halves; k-halves reduced via LDS scratch; plain stores (no atomics).
// AMODE 0: A bf16 [96xK]. AMODE 1 (K=1024): A = sum of 4 fp32 partial slices.
// ---------------------------------------------------------------------------
template<int K, int AMODE>
__global__ __launch_bounds__(512) void gemm_lds(
        const void* __restrict__ Av,
        const float* __restrict__ B0, const float* __restrict__ B1,
        float* __restrict__ C0, float* __restrict__ C1) {
    const float* Bw = blockIdx.z ? B1 : B0;
    float* Cp       = blockIdx.z ? C1 : C0;
    int n0 = blockIdx.x * 64;
    int kc = blockIdx.y;          // k-chunk of 256
    Cp += (size_t)kc * PART;      // each k-chunk writes its own partial slice
    int tid = threadIdx.x, wave = tid >> 6, lane = tid & 63;
    int quad = lane >> 4, l16 = lane & 15;

    __shared__ unsigned short Bs[64 * 264];   // 33792 B
    __shared__ unsigned short As[96 * 264];   // 50688 B

    // ---- stage B: rows n0..n0+63, cols kc*256..+256, fp32 -> bf16
    #pragma unroll
    for (int i = 0; i < 4; i++) {
        int id = tid + 512 * i;
        int r = id >> 5, c = id & 31;
        const float* src = Bw + (size_t)(n0 + r) * K + kc * 256 + c * 8;
        float4 v0 = ld4(src), v1 = ld4(src + 4);
        us8 h;
        h[0] = f2bf(v0.x); h[1] = f2bf(v0.y); h[2] = f2bf(v0.z); h[3] = f2bf(v0.w);
        h[4] = f2bf(v1.x); h[5] = f2bf(v1.y); h[6] = f2bf(v1.z); h[7] = f2bf(v1.w);
        *(us8*)&Bs[r * 264 + c * 8] = h;
    }
    // ---- stage A: rows 0..95, cols kc*256..+256
    #pragma unroll
    for (int i = 0; i < 6; i++) {
        int id = tid + 512 * i;
        int r = id >> 5, c = id & 31;
        if (AMODE == 0) {
            const unsigned short* A = (const unsigned short*)Av;
            *(us8*)&As[r * 264 + c * 8] =
                *(const us8*)(A + (size_t)r * K + kc * 256 + c * 8);
        } else {
            const float* A = (const float*)Av;   // 4 partial slices, K==1024
            const float* s0 = A + (size_t)r * 1024 + kc * 256 + c * 8;
            float4 a0 = ld4(s0), a1 = ld4(s0 + 4);
            #pragma unroll
            for (int p = 1; p < 4; p++) {
                float4 b0 = ld4(s0 + p * PART), b1 = ld4(s0 + p * PART + 4);
                a0.x += b0.x; a0.y += b0.y; a0.z += b0.z; a0.w += b0.w;
                a1.x += b1.x; a1.y += b1.y; a1.z += b1.z; a1.w += b1.w;
            }
            us8 h;
            h[0] = f2bf(a0.x); h[1] = f2bf(a0.y); h[2] = f2bf(a0.z); h[3] = f2bf(a0.w);
            h[4] = f2bf(a1.x); h[5] = f2bf(a1.y); h[6] = f2bf(a1.z); h[7] = f2bf(a1.w);
            *(us8*)&As[r * 264 + c * 8] = h;
        }
    }
    __syncthreads();

    // ---- compute: wave = (strip, khalf); 6 M-tiles x 4 k-steps of 32
    int strip = wave >> 1, kh = wave & 1;
    f32x4 acc[6];
    #pragma unroll
    for (int i = 0; i < 6; i++) acc[i] = (f32x4){0.f, 0.f, 0.f, 0.f};
    const unsigned short* bbase = &Bs[(strip * 16 + l16) * 264 + kh * 128 + quad * 8];
    const unsigned short* abase = &As[l16 * 264 + kh * 128 + quad * 8];
    #pragma unroll
    for (int kk = 0; kk < 128; kk += 32) {
        bf16x8 bfr = __builtin_bit_cast(bf16x8, *(const us8*)(bbase + kk));
        #pragma unroll
        for (int mi = 0; mi < 6; mi++) {
            bf16x8 af = __builtin_bit_cast(bf16x8, *(const us8*)(abase + mi * 16 * 264 + kk));
            acc[mi] = __builtin_amdgcn_mfma_f32_16x16x32_bf16(af, bfr, acc[mi], 0, 0, 0);
        }
    }
    __syncthreads();                       // done reading As; reuse as scratch

    float* scr = (float*)As;               // 4 strips * 6 * 16 * 16 * 4B = 24 KB
    if (kh == 1) {
        #pragma unroll
        for (int mi = 0; mi < 6; mi++)
            #pragma unroll
            for (int r = 0; r < 4; r++)
                scr[((strip * 6 + mi) * 16 + quad * 4 + r) * 16 + l16] = acc[mi][r];
    }
    __syncthreads();
    if (kh == 0) {
        #pragma unroll
        for (int mi = 0; mi < 6; mi++)
            #pragma unroll
            for (int r = 0; r < 4; r++) {
                float v = acc[mi][r] + scr[((strip * 6 + mi) * 16 + quad * 4 + r) * 16 + l16];
                Cp[(size_t)(mi * 16 + quad * 4 + r) * 1024 + n0 + strip * 16 + l16] = v;
            }
    }
}

// ---------------------------------------------------------------------------
// K5: sum 8 presum partials, RMSNorm, emit bf16 summaries. grid 96 x 256.
// ---------------------------------------------------------------------------
__global__ __launch_bounds__(256) void rmsnorm8(
        const float* __restrict__ pp, unsigned short* __restrict__ y) {
    int r = blockIdx.x; int t = threadIdx.x;
    float4 v = (float4){0.f, 0.f, 0.f, 0.f};
    #pragma unroll
    for (int c = 0; c < 8; c++) {
        float4 u = ld4(pp + (size_t)c * PART + (size_t)r * D_ + 4 * t);
        v.x += u.x; v.y += u.y; v.z += u.z; v.w += u.w;
    }
    __shared__ float red[256];
    red[t] = v.x*v.x + v.y*v.y + v.z*v.z + v.w*v.w;
    __syncthreads();
    for (int s2 = 128; s2 > 0; s2 >>= 1) { if (t < s2) red[t] += red[t + s2]; __syncthreads(); }
    float scale = rsqrtf(red[0] * (1.f/1024.f) + RMS_EPS_);
    ushort4 h;
    h.x = f2bf(v.x * scale); h.y = f2bf(v.y * scale);
    h.z = f2bf(v.z * scale); h.w = f2bf(v.w * scale);
    *(ushort4*)(y + (size_t)r * D_ + 4 * t) = h;
}

// ---------------------------------------------------------------------------
// K6: logits/softmax/mix; keys and valsO arrive as 4 fp32 partial slices each.
// grid 256 (b*64+q), block 256.
// ---------------------------------------------------------------------------
__global__ __launch_bounds__(256) void attn_out(
        const float* __restrict__ query, const float* __restrict__ keys_p,
        const float* __restrict__ valsO_p, float* __restrict__ out) {
    int g = blockIdx.x; int b = g >> 6; int q = g & 63;
    int tid = threadIdx.x, wave = tid >> 6, lane = tid & 63;
    __shared__ float attnw[24];
    const float* qrow = query + (size_t)q * D_ + lane * 16;
    float4 qv0 = ld4(qrow), qv1 = ld4(qrow + 4), qv2 = ld4(qrow + 8), qv3 = ld4(qrow + 12);
    for (int s = wave; s < NS; s += 4) {
        const float* krow = keys_p + (size_t)(b * NS + s) * D_ + lane * 16;
        float4 k0 = (float4){0,0,0,0}, k1 = k0, k2 = k0, k3 = k0;
        #pragma unroll
        for (int c = 0; c < 4; c++) {
            const float* kp = krow + (size_t)c * PART;
            float4 u0 = ld4(kp), u1 = ld4(kp + 4), u2 = ld4(kp + 8), u3 = ld4(kp + 12);
            k0.x += u0.x; k0.y += u0.y; k0.z += u0.z; k0.w += u0.w;
            k1.x += u1.x; k1.y += u1.y; k1.z += u1.z; k1.w += u1.w;
            k2.x += u2.x; k2.y += u2.y; k2.z += u2.z; k2.w += u2.w;
            k3.x += u3.x; k3.y += u3.y; k3.z += u3.z; k3.w += u3.w;
        }
        float a = qv0.x*k0.x + qv0.y*k0.y + qv0.z*k0.z + qv0.w*k0.w
                + qv1.x*k1.x + qv1.y*k1.y + qv1.z*k1.z + qv1.w*k1.w
                + qv2.x*k2.x + qv2.y*k2.y + qv2.z*k2.z + qv2.w*k2.w
                + qv3.x*k3.x + qv3.y*k3.y + qv3.z*k3.z + qv3.w*k3.w;
        for (int o = 32; o; o >>= 1) a += __shfl_xor(a, o);
        if (lane == 0) attnw[s] = a * 0.03125f;   // /sqrt(1024)
    }
    __syncthreads();
    if (tid == 0) {
        float mx = -1e30f;
        for (int s = 0; s < NS; s++) mx = fmaxf(mx, attnw[s]);
        float sum = 0.f;
        for (int s = 0; s < NS; s++) { float e = expf(attnw[s] - mx); attnw[s] = e; sum += e; }
        float inv = 1.f / sum;
        for (int s = 0; s < NS; s++) attnw[s] *= inv;
    }
    __syncthreads();
    float ax = 0, ay = 0, az = 0, aw = 0;
    #pragma unroll
    for (int s = 0; s < NS; s++) {
        float w = attnw[s];
        float4 v = (float4){0,0,0,0};
        #pragma unroll
        for (int c = 0; c < 4; c++) {
            float4 u = ld4(valsO_p + (size_t)c * PART + (size_t)(b * NS + s) * D_ + 4 * tid);
            v.x += u.x; v.y += u.y; v.z += u.z; v.w += u.w;
        }
        ax += w * v.x; ay += w * v.y; az += w * v.z; aw += w * v.w;
    }
    float4 o4; o4.x = ax; o4.y = ay; o4.z = az; o4.w = aw;
    *(float4*)(out + (size_t)g * D_ + 4 * tid) = o4;
}

// ---------------------------------------------------------------------------
extern "C" void kernel_launch(void* const* d_in, const int* in_sizes, int n_in,
                              void* d_out, int out_size, void* d_ws, size_t ws_size,
                              hipStream_t stream) {
    (void)in_sizes; (void)n_in; (void)out_size; (void)ws_size;
    const float* ph    = (const float*)d_in[0];
    const float* nll   = (const float*)d_in[1];
    const float* query = (const float*)d_in[2];
    const float* W_sum = (const float*)d_in[3];
    const float* W_k   = (const float*)d_in[4];
    const float* W_v   = (const float*)d_in[5];
    const float* W_o   = (const float*)d_in[6];
    float* out = (float*)d_out;

    char* ws = (char*)d_ws;
    float*          seg_mean = (float*)(ws + 0);                 // 1048576 B
    float*          hid      = (float*)(ws + 1048576);           // 1024 B
    float*          sur      = (float*)(ws + 1049600);           // 1024 B
    unsigned short* feats    = (unsigned short*)(ws + 1050624);  // 393216 B
    float*          presum_p = (float*)(ws + 1443840);           // 8*384KB = 3145728 B
    unsigned short* summ_b   = (unsigned short*)(ws + 4589568);  // 196608 B
    float*          keys_p   = (float*)(ws + 4786176);           // 4*384KB = 1572864 B
    float*          vals_p   = (float*)(ws + 6359040);           // 1572864 B
    float*          valsO_p  = (float*)(ws + 7931904);           // 1572864 B

    seg_stats<<<B_ * NBLK, 512, 0, stream>>>(ph, nll, seg_mean, hid, sur);
    feats_build<<<MPAD, 256, 0, stream>>>(ph, seg_mean, hid, sur, feats);
    gemm_lds<2048, 0><<<dim3(16, 8, 1), 512, 0, stream>>>(
        feats, W_sum, nullptr, presum_p, nullptr);
    rmsnorm8<<<MPAD, 256, 0, stream>>>(presum_p, summ_b);
    gemm_lds<1024, 0><<<dim3(16, 4, 2), 512, 0, stream>>>(
        summ_b, W_k, W_v, keys_p, vals_p);
    gemm_lds<1024, 1><<<dim3(16, 4, 1), 512, 0, stream>>>(
        vals_p, W_o, nullptr, valsO_p, nullptr);
    attn_out<<<B_ * NBLK, 256, 0, stream>>>(query, keys_p, valsO_p, out);
}